// Round 5
// baseline (238.266 us; speedup 1.0000x reference)
//
#include <hip/hip_runtime.h>
#include <stdint.h>

static constexpr int kN = 128;
static constexpr int kTri = (kN * (kN - 1)) / 2;   // 8128 (BT scratch indexing)
static constexpr int kThreads = 1024;
static constexpr float kNeg = -9999.0f;
static constexpr float kThresh = -9000.0f;
static constexpr float kArcBonus = 5.0f;
// Bank-aligned triangular layout: column c padded to a multiple of 8 quads
// (128 B) so every column base sits at bank-quad 0. Total = 8704 quads.
static constexpr int kQuads = 8704;
static constexpr int kDynLds = kQuads * 16;  // 139,264 B (fits 160 KiB pool)
static constexpr int kCMax = 9;              // max row-cache slots per lane

__device__ __forceinline__ int rowBase(int i) { return (i * (2 * kN - 1 - i)) / 2; }
// Padded column base: c = 8q + r -> 8*(q+1)*(4q + r). Every base % 8 == 0, so
// address % 8 (the 16B bank-quad index) == (row + lane_chunk) % 8 -> every
// wave's 64 b128 lanes spread exactly 8 per bank-quad: zero conflicts.
__device__ __forceinline__ int colPad(int c) {
    const int q = c >> 3, r = c & 7;
    return 8 * ((q + 1) * ((q << 2) + r));
}

// LDS-only workgroup barrier: orders LDS without draining vmcnt (wsBT stores
// and vL/vR prefetch loads stay in flight across steps).
__device__ __forceinline__ void ldsBarrier() {
    asm volatile("s_waitcnt lgkmcnt(0)\n\ts_barrier" ::: "memory");
}

// DPP cross-lane reduce helpers -- pure VALU, never touch the LDS pipe.
// Ctrl sequence 0xB1 (xor1), 0x4E (xor2), 0x141 (half-mirror -> 8 lanes),
// 0x140 (row-mirror -> 16 lanes). All source lanes are exec-enabled (the
// reduction runs under wave-uniform waveActive), so bound_ctrl never kicks in.
template <int CTRL>
__device__ __forceinline__ float dppMax(float x) {
    const int y = __builtin_amdgcn_update_dpp(__float_as_int(x), __float_as_int(x),
                                              CTRL, 0xF, 0xF, true);
    return fmaxf(x, __int_as_float(y));
}
template <int CTRL>
__device__ __forceinline__ int dppMinI(int x) {
    const int y = __builtin_amdgcn_update_dpp(x, x, CTRL, 0xF, 0xF, true);
    return (y < x) ? y : x;
}

// Static phase schedule (kN=128, 1024 threads): serial k<=16; P=8 k in
// [17,63]; P=16 [64,127]. P capped at 16 so all reductions are pure DPP.
__device__ __forceinline__ int lpOf(int k) {
    if (k <= 16) return 0;
    if (k < 64) return 3;
    return 4;
}
__device__ __forceinline__ void mapStatic(int nk, int tid, int& i, int& j, bool& act) {
    const int lp = lpOf(nk);
    i = tid >> lp;
    j = i + nk;
    act = i < (kN - nk);
}

// Quad per cell: {x=s00, y=s11, z=s01, w=s10}, padded col-major incl. diagonal.
// Returns the stored quad so callers can mirror it into registers.
__device__ __forceinline__ float4 writeCell(float4* __restrict__ Q4,
                                            uint32_t* __restrict__ wsBT,
                                            int i, int j, int k,
                                            float gb, int ib, float vLc, float vRc,
                                            float v01, int i01, float v11, int i11) {
    const float v00 = (gb + vLc) + kArcBonus;
    const float v10 = (gb + vRc) + kArcBonus;
    const float new10 = (v10 > kThresh) ? v10 : kNeg;
    if (new10 > v11) { v11 = new10; i11 = k; }  // q=j candidate; strict > keeps earlier q
    float4 w = make_float4(kNeg, kNeg, kNeg, kNeg);
    uint32_t p = 0;
    if (v00 > kThresh) { w.x = v00; p |= (uint32_t)(i + ib); }
    if (v01 > kThresh) { w.z = v01; p |= (uint32_t)(i + i01) << 8; }
    if (v10 > kThresh) { w.w = v10; p |= (uint32_t)(i + ib) << 16; }
    if (v11 > kThresh) { w.y = v11; p |= (uint32_t)(i + i11) << 24; }
    Q4[colPad(j) + i] = w;            // one ds_write_b128, conflict-free base
    wsBT[rowBase(i) + k - 1] = p;     // lone global store; not drained per step
    return w;
}

// Serial step (k<=16), k is COMPILE-TIME (caller loop unrolled): one thread per
// cell, i = tid fixed across the whole serial phase, so all row operands
// {s11,s01,s10}(i, i+m) are this thread's OWN previous outputs, mirrored in
// sr[] registers. Only the column stream (other threads' cells) reads LDS.
__device__ __forceinline__ void doStepSerialReg(int k, int tid,
                                                float4* __restrict__ Q4,
                                                uint32_t* __restrict__ wsBT,
                                                const float* __restrict__ v,
                                                int& ci, int& cj, bool& cact,
                                                float& vL, float& vR,
                                                float (&sr11)[17], float (&sr01)[17],
                                                float (&sr10)[17]) {
    const int i = ci, j = cj;
    const bool act = cact;
    const float vLc = vL, vRc = vR;
    float bmax = -3.0e38f, v01 = -3.0e38f, v11 = -3.0e38f;
    int ib = 0, i01 = 0, i11 = 0x7FFFFFFF;
    if (act) {
        const int qjb = colPad(j);
        float4 cur = Q4[qjb + i + 1];  // quad(i+1, j); diagonal zeros when k==1
        bmax = cur.z; ib = 0;          // base(0) = 0 + s01[i+1][j]
        const float p00 = (cur.z + vLc) + kArcBonus;
        v01 = (p00 > kThresh) ? p00 : kNeg; i01 = 0;  // part00 seed
#pragma unroll
        for (int m = 1; m < 16; ++m) {
            if (m < k) {  // compile-time when k is constant-folded
                const float4 nxt = Q4[qjb + i + m + 1];  // quad(q+1, j)
                const float base = sr11[m] + nxt.z;      // s11[i][q] + s01[q+1][j]
                const float p01v = sr01[m] + cur.x;      // s01[i][q] + s00[q][j]
                const float p11v = sr10[m] + cur.y;      // s10[i][q] + s11[q][j]
                if (base > bmax) { bmax = base; ib = m; }  // strict > keeps earliest m
                if (p01v > v01) { v01 = p01v; i01 = m; }
                if (p11v > v11) { v11 = p11v; i11 = m; }
                cur = nxt;
            }
        }
    }
    if (k + 1 < kN) {
        mapStatic(k + 1, tid, ci, cj, cact);
        vL = cact ? v[cj * kN + ci] : 0.f;
        vR = cact ? v[ci * kN + cj] : 0.f;
    }
    if (act) {
        const float4 w = writeCell(Q4, wsBT, i, j, k, bmax, ib, vLc, vRc,
                                   v01, i01, v11, i11);
        sr11[k] = w.y; sr01[k] = w.z; sr10[k] = w.w;  // constant index (k unrolled)
    }
}

// ---- Chunked phases: register row-cache + fw forwarding ----
// Within a phase, i = tid>>LP is FIXED and chart cells are write-once.
//  * Row operands {s11,s01,s10}(i, i+m): preloaded once per phase into r[].
//  * The fresh slot m = k-1 is the cell THIS group computed last step: after
//    the butterfly every lane holds the group max, so it lives in registers
//    (fw11/fw01/fw10). ZERO row LDS reads in steady state.
//  * Column stream: chained reads guarded by m < mhi (verified structure).
template <int LP, int C>
__device__ __forceinline__ void preloadRow(int k0, int tid,
                                           const float4* __restrict__ Q4,
                                           float (&r11)[kCMax], float (&r01)[kCMax],
                                           float (&r10)[kCMax]) {
    constexpr int P = 1 << LP;
    const int i = tid >> LP;
    const int l = tid & (P - 1);
    const int mlo = l * C;
    const int mstart = mlo ? mlo : 1;
    const bool act = i < (kN - k0);
#pragma unroll
    for (int c = 0; c < C; ++c) {
        const int m = mstart + c;
        if (act && (m < mlo + C) && (m <= k0 - 1)) {  // incl. m=k0-1 (visible here)
            const float4 d = Q4[colPad(i + m) + i];  // quad(i, i+m), immutable
            r11[c] = d.y; r01[c] = d.z; r10[c] = d.w;
        }
    }
    // Slots with m > k0-1 stay stale: first read only at step k=m+1, where the
    // isF path substitutes fw and commits it -- stale value never consumed.
}

// Seed fw from the preloaded row slot m = k0-1 (only the owning lane's fw
// matters at the first step of a phase).
template <int LP, int C>
__device__ __forceinline__ void fwInit(int k0, int tid,
                                       const float (&r11)[kCMax], const float (&r01)[kCMax],
                                       const float (&r10)[kCMax],
                                       float& fw11, float& fw01, float& fw10) {
    constexpr int P = 1 << LP;
    const int l = tid & (P - 1);
    const int mlo = l * C;
    const int mstart = mlo ? mlo : 1;
#pragma unroll
    for (int c = 0; c < C; ++c) {
        if (mstart + c == k0 - 1) { fw11 = r11[c]; fw01 = r01[c]; fw10 = r10[c]; }
    }
}

template <int LP, int C>
__device__ __forceinline__ void doStepC(int k, int tid,
                                        float4* __restrict__ Q4,
                                        uint32_t* __restrict__ wsBT,
                                        const float* __restrict__ v,
                                        int& ci, int& cj, bool& cact,
                                        float& vL, float& vR,
                                        float (&r11)[kCMax], float (&r01)[kCMax],
                                        float (&r10)[kCMax],
                                        float& fw11, float& fw01, float& fw10) {
    constexpr int P = 1 << LP;
    static_assert(P <= 16, "reductions must stay pure-DPP");
    const int i = ci, j = cj;
    const bool act = cact;
    const float vLc = vL, vRc = vR;  // prefetch below overwrites vL/vR
    const int l = tid & (P - 1);
    const int mlo = l * C;
    const int mstart = mlo ? mlo : 1;
    const int mhi = (mlo + C < k) ? (mlo + C) : k;
    const bool waveActive = (((tid & ~63) >> LP) < (kN - k));  // wave-uniform

    float bmax = -3.0e38f, v01 = -3.0e38f, v11 = -3.0e38f;
    int ib = 0x7FFFFFFF, i01 = 0x7FFFFFFF, i11 = 0x7FFFFFFF;

    const int mf = k - 1;
    const bool lact = waveActive && act && (mstart < mhi);
    const int qjb = colPad(j);
    float4 cur = make_float4(0.f, 0.f, 0.f, 0.f);
    if (lact) cur = Q4[qjb + i + mstart];  // column seed quad(i+mstart, j)
    if (act && mlo == 0) {
        bmax = cur.z; ib = 0;  // base(0) = 0 + s01[i+1][j]
        const float p00 = (cur.z + vLc) + kArcBonus;
        v01 = (p00 > kThresh) ? p00 : kNeg; i01 = 0;  // part00 seed
    }
#pragma unroll
    for (int c = 0; c < C; ++c) {
        const int m = mstart + c;
        // Row operands: registers; fresh slot m==k-1 comes from fw (the cell
        // this group computed last step), committed into the cache here.
        const bool isF = (m == mf);
        const float a11 = isF ? fw11 : r11[c];
        const float a01 = isF ? fw01 : r01[c];
        const float a10 = isF ? fw10 : r10[c];
        r11[c] = a11; r01[c] = a01; r10[c] = a10;
        const bool on = lact && (m < mhi);
        if (on) {
            const float4 nxt = Q4[qjb + i + m + 1];  // quad(q+1, j); compile-time offset
            const float base = a11 + nxt.z;          // s11[i][q] + s01[q+1][j]
            const float p01v = a01 + cur.x;          // s01[i][q] + s00[q][j]
            const float p11v = a10 + cur.y;          // s10[i][q] + s11[q][j]
            if (base > bmax) { bmax = base; ib = m; }  // strict > keeps earliest m
            if (p01v > v01) { v01 = p01v; i01 = m; }
            if (p11v > v11) { v11 = p11v; i11 = m; }
            cur = nxt;
        }
    }

    // Prefetch next step's mapping + vL/vR (overlaps reduction + barrier).
    if (k + 1 < kN) {
        mapStatic(k + 1, tid, ci, cj, cact);
        vL = cact ? v[cj * kN + ci] : 0.f;
        vR = cact ? v[ci * kN + cj] : 0.f;
    }

    if (waveActive) {
        // Value butterfly (pure DPP, VALU pipe only).
        float gB = dppMax<0x141>(dppMax<0x4E>(dppMax<0xB1>(bmax)));
        float g01 = dppMax<0x141>(dppMax<0x4E>(dppMax<0xB1>(v01)));
        float g11 = dppMax<0x141>(dppMax<0x4E>(dppMax<0xB1>(v11)));
        if constexpr (P == 16) {
            gB = dppMax<0x140>(gB); g01 = dppMax<0x140>(g01); g11 = dppMax<0x140>(g11);
        }
        // Earliest-m argmax: mask losers to INT_MAX, min-butterfly (pure DPP).
        int cB = (bmax == gB) ? ib : 0x7FFFFFFF;
        int c01 = (v01 == g01) ? i01 : 0x7FFFFFFF;
        int c11 = (v11 == g11) ? i11 : 0x7FFFFFFF;
        cB = dppMinI<0x141>(dppMinI<0x4E>(dppMinI<0xB1>(cB)));
        c01 = dppMinI<0x141>(dppMinI<0x4E>(dppMinI<0xB1>(c01)));
        c11 = dppMinI<0x141>(dppMinI<0x4E>(dppMinI<0xB1>(c11)));
        if constexpr (P == 16) {
            cB = dppMinI<0x140>(cB); c01 = dppMinI<0x140>(c01); c11 = dppMinI<0x140>(c11);
        }

        // All lanes now hold the group's written-cell values: keep the row-
        // operand triple in registers for next step's fresh slot (m = k).
        // Identical arithmetic to writeCell => bitwise-equal values.
        const float v10f = (gB + vRc) + kArcBonus;
        const float new10 = (v10f > kThresh) ? v10f : kNeg;
        float v11m = g11;
        if (new10 > v11m) v11m = new10;
        fw11 = (v11m > kThresh) ? v11m : kNeg;  // w.y = s11(i,j)
        fw01 = (g01 > kThresh) ? g01 : kNeg;    // w.z = s01(i,j)
        fw10 = (v10f > kThresh) ? v10f : kNeg;  // w.w = s10(i,j)

        if (act && l == 0) {
            writeCell(Q4, wsBT, i, j, k, gB, cB, vLc, vRc, g01, c01, g11, c11);
        }
    }
}

__global__ __launch_bounds__(kThreads) void eisner_dp(
    const float* __restrict__ vinfo,  // [B][N][N] fp32
    float* __restrict__ outS,         // [B][N][N][2][2] fp32 scores
    float* __restrict__ outBT,        // [B][N][N][2][2] fp32 backtrace (integer-valued)
    uint32_t* __restrict__ btPacked)  // [B][kTri] packed backtrace bytes (d_ws)
{
    extern __shared__ float4 Q4[];

    const int tid = threadIdx.x;
    const int b = blockIdx.x;
    const float* v = vinfo + (size_t)b * kN * kN;
    uint32_t* wsBT = btPacked + (size_t)b * kTri;

    // Diagonal quads = 0. Off-diagonal cells need no init (written before read).
    const float4 zeroq = make_float4(0.f, 0.f, 0.f, 0.f);
    if (tid < kN) Q4[colPad(tid) + tid] = zeroq;

    // Prefetch step-1 mapping + vL/vR.
    int ci, cj; bool cact;
    mapStatic(1, tid, ci, cj, cact);
    float vL = cact ? v[cj * kN + ci] : 0.f;
    float vR = cact ? v[ci * kN + cj] : 0.f;
    __syncthreads();

    // ---- serial phase (k = 1..16), fully unrolled so sr indices are constant;
    // own-row operands live entirely in registers ----
    {
        float sr11[17], sr01[17], sr10[17];
#pragma unroll
        for (int k = 1; k <= 16; ++k) {
            doStepSerialReg(k, tid, Q4, wsBT, v, ci, cj, cact, vL, vR,
                            sr11, sr01, sr10);
            ldsBarrier();
        }
    }

    // Row caches (registers); slots filled by preloadRow + fw commits.
    float r11[kCMax], r01[kCMax], r10[kCMax];
    float fw11 = kNeg, fw01 = kNeg, fw10 = kNeg;
#pragma unroll
    for (int c = 0; c < kCMax; ++c) { r11[c] = kNeg; r01[c] = kNeg; r10[c] = kNeg; }

    // P=8 phase split: C=5 while k<40 (8*5=40 >= 39), C=9 after (72 >= 63).
    preloadRow<3, 5>(17, tid, Q4, r11, r01, r10);
    fwInit<3, 5>(17, tid, r11, r01, r10, fw11, fw01, fw10);
    for (int k = 17; k < 40; ++k) {
        doStepC<3, 5>(k, tid, Q4, wsBT, v, ci, cj, cact, vL, vR,
                      r11, r01, r10, fw11, fw01, fw10);
        ldsBarrier();
    }
    preloadRow<3, 9>(40, tid, Q4, r11, r01, r10);
    fwInit<3, 9>(40, tid, r11, r01, r10, fw11, fw01, fw10);
    for (int k = 40; k < 64; ++k) {
        doStepC<3, 9>(k, tid, Q4, wsBT, v, ci, cj, cact, vL, vR,
                      r11, r01, r10, fw11, fw01, fw10);
        ldsBarrier();
    }
    // P=16 phases: pure-DPP reductions. C=7: 16*7=112 >= 111; C=9: 144 >= 127.
    preloadRow<4, 7>(64, tid, Q4, r11, r01, r10);
    fwInit<4, 7>(64, tid, r11, r01, r10, fw11, fw01, fw10);
    for (int k = 64; k < 112; ++k) {
        doStepC<4, 7>(k, tid, Q4, wsBT, v, ci, cj, cact, vL, vR,
                      r11, r01, r10, fw11, fw01, fw10);
        ldsBarrier();
    }
    preloadRow<4, 9>(112, tid, Q4, r11, r01, r10);
    fwInit<4, 9>(112, tid, r11, r01, r10, fw11, fw01, fw10);
    for (int k = 112; k < 128; ++k) {
        doStepC<4, 9>(k, tid, Q4, wsBT, v, ci, cj, cact, vL, vR,
                      r11, r01, r10, fw11, fw01, fw10);
        ldsBarrier();
    }

    // Full barrier (drains vmcnt) before reading wsBT back.
    __syncthreads();

    // ---- epilogue: emit full [N][N][2][2] scores + backtrace, coalesced ----
    float4* gS4 = (float4*)(outS + (size_t)b * kN * kN * 4);
    float4* gB4 = (float4*)(outBT + (size_t)b * kN * kN * 4);
    const float4 negq = make_float4(kNeg, kNeg, kNeg, kNeg);
    for (int c = tid; c < kN * kN; c += kThreads) {
        const int i = c >> 7, j = c & (kN - 1);
        if (i < j) {
            const float4 q = Q4[colPad(j) + i];
            gS4[c] = make_float4(q.x, q.z, q.w, q.y);  // {s00, s01, s10, s11}
            const uint32_t p = wsBT[rowBase(i) + (j - i - 1)];
            gB4[c] = make_float4((float)(p & 255u), (float)((p >> 8) & 255u),
                                 (float)((p >> 16) & 255u), (float)(p >> 24));
        } else if (i == j) {
            gS4[c] = zeroq;
            gB4[c] = zeroq;
        } else {
            gS4[c] = negq;
            gB4[c] = zeroq;
        }
    }
}

extern "C" void kernel_launch(void* const* d_in, const int* in_sizes, int n_in,
                              void* d_out, int out_size, void* d_ws, size_t ws_size,
                              hipStream_t stream) {
    (void)n_in; (void)out_size; (void)ws_size;
    const float* vinfo = (const float*)d_in[0];  // fp32 [B][N][N]
    const int B = in_sizes[1];                   // b_buffer_size has B elements
    float* outS = (float*)d_out;
    float* outBT = outS + (size_t)B * kN * kN * 4;
    uint32_t* btPacked = (uint32_t*)d_ws;        // needs B*kTri*4 = ~2.1 MB

    hipFuncSetAttribute(reinterpret_cast<const void*>(eisner_dp),
                        hipFuncAttributeMaxDynamicSharedMemorySize, kDynLds);

    eisner_dp<<<dim3(B), dim3(kThreads), kDynLds, stream>>>(vinfo, outS, outBT, btPacked);
}